// Round 4
// baseline (153.326 us; speedup 1.0000x reference)
//
#include <hip/hip_runtime.h>
#include <hip/hip_fp16.h>

// SVD++ scoring, item-major restructure.
// out[b] = mu + b_u + b_i + q_b.p_u + rsqrt(len)*sum_{l<len} q_b . y[hist[b][l]]
// Instead of gathering random y-rows (L2-miss-fabric bound at ~3.2 TB/s), invert:
//   K1: build dense fp16 Q[8192][128] (2MB, L2-resident) + base/norm; and
//       counting-scatter pairs (b) into per-item buckets (CAP=16) + spill list.
//   K2: stream implicit_emb sequentially (one wave per 4 items/block); for each
//       referencing b, dot(y_j, Q[b]) by 16-lane groups; atomicAdd into S[b].
//       Tail blocks process the (rare, ~hundreds) bucket-overflow spill pairs.
//   K3: out[b] = base[b] + norm[b]*S[b].

#define BB     8192
#define DD     128
#define LL     200
#define NITEMS 100000
#define CAP    16

#define QB_BLOCKS    2048                 // 8192 waves, one per b
#define SC_BLOCKS    ((BB * LL) / 256)    // 6400, exact
#define ITEM_BLOCKS  (NITEMS / 4)         // 25000, 4 items (waves) per block
#define SPILL_BLOCKS 64

// ws byte offsets (16B aligned)
#define OFF_COUNTS   0u          // NITEMS*4            = 400000
#define OFF_S        400000u     // BB*4                = 32768
#define OFF_SPILLCNT 432768u     // 4 (+pad)
#define ZERO_BYTES   432896u
#define OFF_Q        432896u     // BB*DD*2             = 2097152
#define OFF_BASE     2530048u    // BB*4
#define OFF_NORM     2562816u    // BB*4
#define OFF_BUCKET   2595584u    // NITEMS*CAP*4        = 6400000
#define OFF_SPILL    8995584u    // BB*LL*2*4           = 13107200
#define WS_NEEDED    22102784u

__global__ __launch_bounds__(256) void k1_build(
    const int* __restrict__ user_ids,
    const int* __restrict__ item_ids,
    const int* __restrict__ hist_items,
    const int* __restrict__ hist_len,
    const float* __restrict__ user_emb,
    const float* __restrict__ item_emb,
    const float* __restrict__ user_bias,
    const float* __restrict__ item_bias,
    const float* __restrict__ global_bias,
    int* __restrict__ counts,
    float* __restrict__ base,
    float* __restrict__ norm,
    __half* __restrict__ Q,
    int* __restrict__ bucket,
    int* __restrict__ spill,
    int* __restrict__ spillCnt)
{
    if (blockIdx.x < QB_BLOCKS) {
        // Role A: one wave per batch element: build Q (fp16), base, norm.
        const int b    = blockIdx.x * 4 + (threadIdx.x >> 6);
        const int lane = threadIdx.x & 63;
        const int it   = item_ids[b];
        const int u    = user_ids[b];
        const float2 qv = *reinterpret_cast<const float2*>(item_emb + (size_t)it * DD + lane * 2);
        const float2 pv = *reinterpret_cast<const float2*>(user_emb + (size_t)u  * DD + lane * 2);
        reinterpret_cast<__half2*>(Q)[(size_t)b * (DD / 2) + lane] = __floats2half2_rn(qv.x, qv.y);
        float d = qv.x * pv.x + qv.y * pv.y;
        d += __shfl_down(d, 32, 64);
        d += __shfl_down(d, 16, 64);
        d += __shfl_down(d, 8, 64);
        d += __shfl_down(d, 4, 64);
        d += __shfl_down(d, 2, 64);
        d += __shfl_down(d, 1, 64);
        if (lane == 0) {
            const int len = hist_len[b];
            base[b] = global_bias[0] + user_bias[u] + item_bias[it] + d;
            norm[b] = (len > 0) ? rsqrtf((float)len) : 0.f;
        }
    } else {
        // Role B: flat over all (b,l) pairs: counting-scatter into buckets.
        const int t = (blockIdx.x - QB_BLOCKS) * 256 + threadIdx.x;  // < BB*LL exactly
        const int b = t / LL;
        const int l = t - b * LL;
        if (l < hist_len[b]) {
            const int j   = hist_items[t];
            const int pos = atomicAdd(&counts[j], 1);
            if (pos < CAP) {
                bucket[j * CAP + pos] = b;
            } else {
                const int sp = atomicAdd(spillCnt, 1);
                spill[2 * sp]     = b;
                spill[2 * sp + 1] = j;
            }
        }
    }
}

__device__ __forceinline__ float dot8(const float4 hraw, const float4 y0, const float4 y1) {
    const __half2* h = reinterpret_cast<const __half2*>(&hraw);
    const float2 a = __half22float2(h[0]);
    const float2 b = __half22float2(h[1]);
    const float2 c = __half22float2(h[2]);
    const float2 d = __half22float2(h[3]);
    return a.x * y0.x + a.y * y0.y + b.x * y0.z + b.y * y0.w
         + c.x * y1.x + c.y * y1.y + d.x * y1.z + d.y * y1.w;
}

__global__ __launch_bounds__(256) void k2_stream(
    const float* __restrict__ implicit_emb,
    const __half* __restrict__ Q,
    const int* __restrict__ counts,
    const int* __restrict__ bucket,
    const int* __restrict__ spill,
    const int* __restrict__ spillCnt,
    float* __restrict__ S)
{
    const int w    = threadIdx.x >> 6;
    const int lane = threadIdx.x & 63;

    if (blockIdx.x < ITEM_BLOCKS) {
        const int j = blockIdx.x * 4 + w;      // < NITEMS exactly
        int cnt = counts[j];
        if (cnt <= 0) return;
        if (cnt > CAP) cnt = CAP;

        const int g  = lane >> 4;              // 4 groups of 16 lanes
        const int gl = lane & 15;              // 8 dims per lane
        const float* yrow = implicit_emb + (size_t)j * DD + gl * 8;
        const float4 y0 = *reinterpret_cast<const float4*>(yrow);
        const float4 y1 = *reinterpret_cast<const float4*>(yrow + 4);
        const int* bk = bucket + j * CAP;

        int i = g;
        for (; i + 4 < cnt; i += 8) {          // 2 entries per group in flight
            const int b0 = bk[i];
            const int b1 = bk[i + 4];
            const float4 h0 = *reinterpret_cast<const float4*>(Q + (size_t)b0 * DD + gl * 8);
            const float4 h1 = *reinterpret_cast<const float4*>(Q + (size_t)b1 * DD + gl * 8);
            float d0 = dot8(h0, y0, y1);
            float d1 = dot8(h1, y0, y1);
            d0 += __shfl_xor(d0, 8, 64); d1 += __shfl_xor(d1, 8, 64);
            d0 += __shfl_xor(d0, 4, 64); d1 += __shfl_xor(d1, 4, 64);
            d0 += __shfl_xor(d0, 2, 64); d1 += __shfl_xor(d1, 2, 64);
            d0 += __shfl_xor(d0, 1, 64); d1 += __shfl_xor(d1, 1, 64);
            if (gl == 0) {
                atomicAdd(&S[b0], d0);
                atomicAdd(&S[b1], d1);
            }
        }
        if (i < cnt) {
            const int b0 = bk[i];
            const float4 h0 = *reinterpret_cast<const float4*>(Q + (size_t)b0 * DD + gl * 8);
            float d0 = dot8(h0, y0, y1);
            d0 += __shfl_xor(d0, 8, 64);
            d0 += __shfl_xor(d0, 4, 64);
            d0 += __shfl_xor(d0, 2, 64);
            d0 += __shfl_xor(d0, 1, 64);
            if (gl == 0) atomicAdd(&S[b0], d0);
        }
    } else {
        // Spill pairs: one wave per pair, grid-stride. Typically a few hundred.
        const int nspill = *spillCnt;
        int e = (blockIdx.x - ITEM_BLOCKS) * 4 + w;
        for (; e < nspill; e += SPILL_BLOCKS * 4) {
            const int b = spill[2 * e];
            const int j = spill[2 * e + 1];
            const float2 y  = *reinterpret_cast<const float2*>(implicit_emb + (size_t)j * DD + lane * 2);
            const float2 qf = __half22float2(reinterpret_cast<const __half2*>(Q)[(size_t)b * (DD / 2) + lane]);
            float d = qf.x * y.x + qf.y * y.y;
            d += __shfl_down(d, 32, 64);
            d += __shfl_down(d, 16, 64);
            d += __shfl_down(d, 8, 64);
            d += __shfl_down(d, 4, 64);
            d += __shfl_down(d, 2, 64);
            d += __shfl_down(d, 1, 64);
            if (lane == 0) atomicAdd(&S[b], d);
        }
    }
}

__global__ __launch_bounds__(256) void k3_final(
    const float* __restrict__ base,
    const float* __restrict__ norm,
    const float* __restrict__ S,
    float* __restrict__ out)
{
    const int b = blockIdx.x * 256 + threadIdx.x;
    if (b < BB) out[b] = base[b] + norm[b] * S[b];
}

// Fallback (no-workspace): R2 balanced gather kernel, fp32.
__global__ __launch_bounds__(256) void svdpp_fp32_kernel(
    const int* __restrict__ user_ids,
    const int* __restrict__ item_ids,
    const int* __restrict__ hist_items,
    const int* __restrict__ hist_len,
    const float* __restrict__ user_emb,
    const float* __restrict__ item_emb,
    const float* __restrict__ implicit_emb,
    const float* __restrict__ user_bias,
    const float* __restrict__ item_bias,
    const float* __restrict__ global_bias,
    float* __restrict__ out)
{
    const int b    = blockIdx.x;
    const int tid  = threadIdx.x;
    const int w    = tid >> 6;
    const int lane = tid & 63;
    const int half = lane >> 5;
    const int sub  = (w << 1) | half;
    const int d0   = (lane & 31) << 2;

    const int len = hist_len[b];
    const int it  = item_ids[b];
    const float4 q = *reinterpret_cast<const float4*>(item_emb + (size_t)it * DD + d0);
    const int* __restrict__ hrow = hist_items + (size_t)b * LL;

    float4 acc = make_float4(0.f, 0.f, 0.f, 0.f);
    int l = sub;
    for (; l + 8 < len; l += 16) {
        const int j0 = hrow[l];
        const int j1 = hrow[l + 8];
        const float4 y0 = *reinterpret_cast<const float4*>(implicit_emb + (size_t)j0 * DD + d0);
        const float4 y1 = *reinterpret_cast<const float4*>(implicit_emb + (size_t)j1 * DD + d0);
        acc.x += y0.x; acc.y += y0.y; acc.z += y0.z; acc.w += y0.w;
        acc.x += y1.x; acc.y += y1.y; acc.z += y1.z; acc.w += y1.w;
    }
    if (l < len) {
        const int j = hrow[l];
        const float4 y = *reinterpret_cast<const float4*>(implicit_emb + (size_t)j * DD + d0);
        acc.x += y.x; acc.y += y.y; acc.z += y.z; acc.w += y.w;
    }

    acc.x += __shfl_xor(acc.x, 32, 64);
    acc.y += __shfl_xor(acc.y, 32, 64);
    acc.z += __shfl_xor(acc.z, 32, 64);
    acc.w += __shfl_xor(acc.w, 32, 64);

    float s = q.x * acc.x + q.y * acc.y + q.z * acc.z + q.w * acc.w;
    s += __shfl_down(s, 16, 64);
    s += __shfl_down(s, 8, 64);
    s += __shfl_down(s, 4, 64);
    s += __shfl_down(s, 2, 64);
    s += __shfl_down(s, 1, 64);

    __shared__ float partial[4];
    if (lane == 0) partial[w] = s;
    __syncthreads();

    if (w == 0) {
        const int u = user_ids[b];
        const float4 p = *reinterpret_cast<const float4*>(user_emb + (size_t)u * DD + d0);
        float bs = p.x * q.x + p.y * q.y + p.z * q.z + p.w * q.w;
        bs += __shfl_down(bs, 16, 64);
        bs += __shfl_down(bs, 8, 64);
        bs += __shfl_down(bs, 4, 64);
        bs += __shfl_down(bs, 2, 64);
        bs += __shfl_down(bs, 1, 64);
        if (lane == 0) {
            const float S = partial[0] + partial[1] + partial[2] + partial[3];
            const float norm = (len > 0) ? rsqrtf((float)len) : 0.f;
            out[b] = global_bias[0] + user_bias[u] + item_bias[it] + bs + norm * S;
        }
    }
}

extern "C" void kernel_launch(void* const* d_in, const int* in_sizes, int n_in,
                              void* d_out, int out_size, void* d_ws, size_t ws_size,
                              hipStream_t stream) {
    const int*   user_ids     = (const int*)d_in[0];
    const int*   item_ids     = (const int*)d_in[1];
    const int*   hist_items   = (const int*)d_in[2];
    const int*   hist_len     = (const int*)d_in[3];
    const float* user_emb     = (const float*)d_in[4];
    const float* item_emb     = (const float*)d_in[5];
    const float* implicit_emb = (const float*)d_in[6];
    const float* user_bias    = (const float*)d_in[7];
    const float* item_bias    = (const float*)d_in[8];
    const float* global_bias  = (const float*)d_in[9];
    float* out = (float*)d_out;

    if (ws_size < (size_t)WS_NEEDED) {
        svdpp_fp32_kernel<<<BB, 256, 0, stream>>>(
            user_ids, item_ids, hist_items, hist_len,
            user_emb, item_emb, implicit_emb,
            user_bias, item_bias, global_bias, out);
        return;
    }

    char* ws = (char*)d_ws;
    int*    counts   = (int*)   (ws + OFF_COUNTS);
    float*  S        = (float*) (ws + OFF_S);
    int*    spillCnt = (int*)   (ws + OFF_SPILLCNT);
    __half* Q        = (__half*)(ws + OFF_Q);
    float*  base     = (float*) (ws + OFF_BASE);
    float*  norm     = (float*) (ws + OFF_NORM);
    int*    bucket   = (int*)   (ws + OFF_BUCKET);
    int*    spill    = (int*)   (ws + OFF_SPILL);

    hipMemsetAsync(ws, 0, ZERO_BYTES, stream);  // counts + S + spillCnt

    k1_build<<<QB_BLOCKS + SC_BLOCKS, 256, 0, stream>>>(
        user_ids, item_ids, hist_items, hist_len,
        user_emb, item_emb, user_bias, item_bias, global_bias,
        counts, base, norm, Q, bucket, spill, spillCnt);

    k2_stream<<<ITEM_BLOCKS + SPILL_BLOCKS, 256, 0, stream>>>(
        implicit_emb, Q, counts, bucket, spill, spillCnt, S);

    k3_final<<<(BB + 255) / 256, 256, 0, stream>>>(base, norm, S, out);
}

// Round 5
// 68.277 us; speedup vs baseline: 2.2457x; 2.2457x over previous
//
#include <hip/hip_runtime.h>
#include <hip/hip_fp16.h>

// SVD++ scoring with XCD-spatial item slicing.
// out[b] = mu + b_u + b_i + q_b.p_u + rsqrt(len)*sum_{l<len} q_b . y[hist[b][l]]
//
// K0 (fused roles): (a) implicit_emb fp32->fp16 table (25.6 MB) in ws;
//                   (b) Q[8192][128] fp16 + base[b] (mu+b_u+b_i+q.p) + norm[b];
//                   (c) per-b LDS counting sort of history indices into 8 item
//                       slices (12500 items each) -> sidx[b][200] + soffs[b][9].
// K2: block g -> slice x=g&7 (lands on XCD x under round-robin mapping), chunk
//     c=g>>3 of 4 b's (wave per b). Each XCD then only gathers its 3.2 MB fp16
//     slice -> L2-resident. Q/lists read nontemporally to preserve L2 capacity.
//     Writes part[b*8+x] (unique writer, no atomics).
// K3: out[b] = base[b] + norm[b]*sum_x part[b*8+x].

#define BB     8192
#define DD     128
#define LL     200
#define NITEMS 100000
#define NSLICE 8
#define SLICE_W 12500

#define CONV_BLOCKS 6250   // 12.8M floats / 8 per thread / 256 threads (exact)
#define QB_BLOCKS   2048   // 4 waves/block, wave per b
#define SORT_BLOCKS 8192   // block per b
#define K2_BLOCKS   16384  // 2048 chunks * 8 slices

// ws layout (bytes)
#define OFF_IMP16 0u          // 100000*128*2 = 25,600,000
#define OFF_Q     25600000u   // 8192*128*2   =  2,097,152
#define OFF_SIDX  27697152u   // 8192*200*4   =  6,553,600
#define OFF_OFFS  34250752u   // 8192*9*4     =    294,912
#define OFF_PART  34545664u   // 8192*8*4     =    262,144
#define OFF_BASE  34807808u   // 8192*4
#define OFF_NORM  34840576u   // 8192*4
#define WS_FULL   34873344u
#define IMP16_BYTES 25600000u

struct __align__(8) half4 { __half2 a, b; };
union h4u { unsigned long long u; half4 h; };

__device__ __forceinline__ void acc_row(float4& acc, const half4 r) {
    const float2 lo = __half22float2(r.a);
    const float2 hi = __half22float2(r.b);
    acc.x += lo.x; acc.y += lo.y; acc.z += hi.x; acc.w += hi.y;
}

__global__ __launch_bounds__(256) void k0_prep(
    const int* __restrict__ user_ids,
    const int* __restrict__ item_ids,
    const int* __restrict__ hist_items,
    const int* __restrict__ hist_len,
    const float* __restrict__ user_emb,
    const float* __restrict__ item_emb,
    const float* __restrict__ implicit_emb,
    const float* __restrict__ user_bias,
    const float* __restrict__ item_bias,
    const float* __restrict__ global_bias,
    __half* __restrict__ imp16,
    __half* __restrict__ Q,
    int* __restrict__ sidx,
    int* __restrict__ soffs,
    float* __restrict__ base,
    float* __restrict__ norm)
{
    const int g = blockIdx.x;
    if (g < CONV_BLOCKS) {
        // Role A: fp32 -> fp16 convert, 8 floats per thread.
        const int i = g * 256 + threadIdx.x;          // < 1.6M exactly
        const float4 v0 = reinterpret_cast<const float4*>(implicit_emb)[2 * i];
        const float4 v1 = reinterpret_cast<const float4*>(implicit_emb)[2 * i + 1];
        half4 h0, h1;
        h0.a = __floats2half2_rn(v0.x, v0.y); h0.b = __floats2half2_rn(v0.z, v0.w);
        h1.a = __floats2half2_rn(v1.x, v1.y); h1.b = __floats2half2_rn(v1.z, v1.w);
        reinterpret_cast<half4*>(imp16)[2 * i]     = h0;
        reinterpret_cast<half4*>(imp16)[2 * i + 1] = h1;
    } else if (g < CONV_BLOCKS + QB_BLOCKS) {
        // Role B: wave per b -> Q fp16 row, base, norm.
        const int b    = (g - CONV_BLOCKS) * 4 + (threadIdx.x >> 6);
        const int lane = threadIdx.x & 63;
        const int it   = item_ids[b];
        const int u    = user_ids[b];
        const float2 qv = *reinterpret_cast<const float2*>(item_emb + (size_t)it * DD + lane * 2);
        const float2 pv = *reinterpret_cast<const float2*>(user_emb + (size_t)u  * DD + lane * 2);
        reinterpret_cast<__half2*>(Q)[b * (DD / 2) + lane] = __floats2half2_rn(qv.x, qv.y);
        float d = qv.x * pv.x + qv.y * pv.y;
        d += __shfl_down(d, 32, 64);
        d += __shfl_down(d, 16, 64);
        d += __shfl_down(d, 8, 64);
        d += __shfl_down(d, 4, 64);
        d += __shfl_down(d, 2, 64);
        d += __shfl_down(d, 1, 64);
        if (lane == 0) {
            const int len = hist_len[b];
            base[b] = global_bias[0] + user_bias[u] + item_bias[it] + d;
            norm[b] = (len > 0) ? rsqrtf((float)len) : 0.f;
        }
    } else {
        // Role C: block per b -> counting sort of history indices by slice.
        const int b = g - CONV_BLOCKS - QB_BLOCKS;
        __shared__ int cnt[NSLICE], fill[NSLICE], offs_s[NSLICE + 1];
        const int t = threadIdx.x;
        if (t < NSLICE) { cnt[t] = 0; fill[t] = 0; }
        __syncthreads();
        const int len = hist_len[b];
        int j = -1, s = -1;
        if (t < len) {
            j = hist_items[b * LL + t];
            s = j / SLICE_W;
            atomicAdd(&cnt[s], 1);          // LDS atomic (fast)
        }
        __syncthreads();
        if (t == 0) {
            offs_s[0] = 0;
            for (int x = 0; x < NSLICE; ++x) offs_s[x + 1] = offs_s[x] + cnt[x];
        }
        __syncthreads();
        if (t <= NSLICE) soffs[b * 9 + t] = offs_s[t];
        if (t < len) {
            const int pos = offs_s[s] + atomicAdd(&fill[s], 1);
            sidx[b * LL + pos] = j;
        }
    }
}

__global__ __launch_bounds__(256) void k2_gather(
    const __half* __restrict__ imp16,
    const __half* __restrict__ Q,
    const int* __restrict__ sidx,
    const int* __restrict__ soffs,
    float* __restrict__ part)
{
    const int g    = blockIdx.x;
    const int x    = g & 7;        // slice; under round-robin, == XCD id
    const int c    = g >> 3;       // chunk of 4 batch elements
    const int w    = threadIdx.x >> 6;
    const int b    = c * 4 + w;
    const int lane = threadIdx.x & 63;
    const int h    = lane >> 5;    // two halves split the list
    const int gl   = lane & 31;    // 4 dims (halfs) per lane

    const int off0 = __builtin_nontemporal_load(soffs + b * 9 + x);
    const int off1 = __builtin_nontemporal_load(soffs + b * 9 + x + 1);
    const int n    = off1 - off0;

    h4u qr;
    qr.u = __builtin_nontemporal_load(
        reinterpret_cast<const unsigned long long*>(Q + (size_t)b * DD) + gl);
    const float2 qlo = __half22float2(qr.h.a);
    const float2 qhi = __half22float2(qr.h.b);

    const int* lst = sidx + b * LL + off0;
    float4 acc = make_float4(0.f, 0.f, 0.f, 0.f);

    int i = h;
    for (; i + 6 < n; i += 8) {            // 4 rows in flight per half-wave
        const int j0 = __builtin_nontemporal_load(lst + i);
        const int j1 = __builtin_nontemporal_load(lst + i + 2);
        const int j2 = __builtin_nontemporal_load(lst + i + 4);
        const int j3 = __builtin_nontemporal_load(lst + i + 6);
        const half4 r0 = *reinterpret_cast<const half4*>(imp16 + (size_t)j0 * DD + gl * 4);
        const half4 r1 = *reinterpret_cast<const half4*>(imp16 + (size_t)j1 * DD + gl * 4);
        const half4 r2 = *reinterpret_cast<const half4*>(imp16 + (size_t)j2 * DD + gl * 4);
        const half4 r3 = *reinterpret_cast<const half4*>(imp16 + (size_t)j3 * DD + gl * 4);
        acc_row(acc, r0); acc_row(acc, r1); acc_row(acc, r2); acc_row(acc, r3);
    }
    for (; i < n; i += 2) {
        const int j = __builtin_nontemporal_load(lst + i);
        const half4 r = *reinterpret_cast<const half4*>(imp16 + (size_t)j * DD + gl * 4);
        acc_row(acc, r);
    }

    // merge the two halves (disjoint list entries, same dim range)
    acc.x += __shfl_xor(acc.x, 32, 64);
    acc.y += __shfl_xor(acc.y, 32, 64);
    acc.z += __shfl_xor(acc.z, 32, 64);
    acc.w += __shfl_xor(acc.w, 32, 64);

    float s = qlo.x * acc.x + qlo.y * acc.y + qhi.x * acc.z + qhi.y * acc.w;
    s += __shfl_down(s, 16, 64);
    s += __shfl_down(s, 8, 64);
    s += __shfl_down(s, 4, 64);
    s += __shfl_down(s, 2, 64);
    s += __shfl_down(s, 1, 64);

    if (lane == 0) part[b * 8 + x] = s;    // unconditional: n==0 stores 0
}

__global__ __launch_bounds__(256) void k3_final(
    const float* __restrict__ base,
    const float* __restrict__ norm,
    const float* __restrict__ part,
    float* __restrict__ out)
{
    const int b = blockIdx.x * 256 + threadIdx.x;
    if (b >= BB) return;
    const float4 p0 = reinterpret_cast<const float4*>(part)[b * 2];
    const float4 p1 = reinterpret_cast<const float4*>(part)[b * 2 + 1];
    const float s = ((p0.x + p0.y) + (p0.z + p0.w)) + ((p1.x + p1.y) + (p1.z + p1.w));
    out[b] = base[b] + norm[b] * s;
}

// ---------- fallback paths ----------

__global__ __launch_bounds__(256) void convert_kernel(
    const float* __restrict__ in, __half* __restrict__ out, int n8)
{
    int i = blockIdx.x * blockDim.x + threadIdx.x;
    if (i >= n8) return;
    const float4 v0 = reinterpret_cast<const float4*>(in)[2 * i];
    const float4 v1 = reinterpret_cast<const float4*>(in)[2 * i + 1];
    half4 h0, h1;
    h0.a = __floats2half2_rn(v0.x, v0.y); h0.b = __floats2half2_rn(v0.z, v0.w);
    h1.a = __floats2half2_rn(v1.x, v1.y); h1.b = __floats2half2_rn(v1.z, v1.w);
    reinterpret_cast<half4*>(out)[2 * i]     = h0;
    reinterpret_cast<half4*>(out)[2 * i + 1] = h1;
}

__global__ __launch_bounds__(256) void svdpp_fp16_kernel(
    const int* __restrict__ user_ids,
    const int* __restrict__ item_ids,
    const int* __restrict__ hist_items,
    const int* __restrict__ hist_len,
    const float* __restrict__ user_emb,
    const float* __restrict__ item_emb,
    const __half* __restrict__ imp16,
    const float* __restrict__ user_bias,
    const float* __restrict__ item_bias,
    const float* __restrict__ global_bias,
    float* __restrict__ out)
{
    const int b    = blockIdx.x;
    const int tid  = threadIdx.x;
    const int w    = tid >> 6;
    const int lane = tid & 63;
    const int half = lane >> 5;
    const int sub  = (w << 1) | half;
    const int d0   = (lane & 31) << 2;

    __shared__ int   hidx[LL];
    __shared__ float partial[4];

    const int len = hist_len[b];
    const int it  = item_ids[b];
    if (tid < LL) hidx[tid] = hist_items[(size_t)b * LL + tid];
    __syncthreads();

    const float4 q = *reinterpret_cast<const float4*>(item_emb + (size_t)it * DD + d0);
    float4 acc = make_float4(0.f, 0.f, 0.f, 0.f);
    int l = sub;
    for (; l + 24 < len; l += 32) {
        const int j0 = hidx[l];
        const int j1 = hidx[l + 8];
        const int j2 = hidx[l + 16];
        const int j3 = hidx[l + 24];
        const half4 r0 = *reinterpret_cast<const half4*>(imp16 + (size_t)j0 * DD + d0);
        const half4 r1 = *reinterpret_cast<const half4*>(imp16 + (size_t)j1 * DD + d0);
        const half4 r2 = *reinterpret_cast<const half4*>(imp16 + (size_t)j2 * DD + d0);
        const half4 r3 = *reinterpret_cast<const half4*>(imp16 + (size_t)j3 * DD + d0);
        acc_row(acc, r0); acc_row(acc, r1); acc_row(acc, r2); acc_row(acc, r3);
    }
    for (; l < len; l += 8) {
        const int j = hidx[l];
        const half4 r = *reinterpret_cast<const half4*>(imp16 + (size_t)j * DD + d0);
        acc_row(acc, r);
    }

    acc.x += __shfl_xor(acc.x, 32, 64);
    acc.y += __shfl_xor(acc.y, 32, 64);
    acc.z += __shfl_xor(acc.z, 32, 64);
    acc.w += __shfl_xor(acc.w, 32, 64);

    float s = q.x * acc.x + q.y * acc.y + q.z * acc.z + q.w * acc.w;
    s += __shfl_down(s, 16, 64);
    s += __shfl_down(s, 8, 64);
    s += __shfl_down(s, 4, 64);
    s += __shfl_down(s, 2, 64);
    s += __shfl_down(s, 1, 64);
    if (lane == 0) partial[w] = s;
    __syncthreads();

    if (w == 0) {
        const int u = user_ids[b];
        const float4 p = *reinterpret_cast<const float4*>(user_emb + (size_t)u * DD + d0);
        float bs = p.x * q.x + p.y * q.y + p.z * q.z + p.w * q.w;
        bs += __shfl_down(bs, 16, 64);
        bs += __shfl_down(bs, 8, 64);
        bs += __shfl_down(bs, 4, 64);
        bs += __shfl_down(bs, 2, 64);
        bs += __shfl_down(bs, 1, 64);
        if (lane == 0) {
            const float S = partial[0] + partial[1] + partial[2] + partial[3];
            const float nr = (len > 0) ? rsqrtf((float)len) : 0.f;
            out[b] = global_bias[0] + user_bias[u] + item_bias[it] + bs + nr * S;
        }
    }
}

__global__ __launch_bounds__(256) void svdpp_fp32_kernel(
    const int* __restrict__ user_ids,
    const int* __restrict__ item_ids,
    const int* __restrict__ hist_items,
    const int* __restrict__ hist_len,
    const float* __restrict__ user_emb,
    const float* __restrict__ item_emb,
    const float* __restrict__ implicit_emb,
    const float* __restrict__ user_bias,
    const float* __restrict__ item_bias,
    const float* __restrict__ global_bias,
    float* __restrict__ out)
{
    const int b    = blockIdx.x;
    const int tid  = threadIdx.x;
    const int w    = tid >> 6;
    const int lane = tid & 63;
    const int half = lane >> 5;
    const int sub  = (w << 1) | half;
    const int d0   = (lane & 31) << 2;

    const int len = hist_len[b];
    const int it  = item_ids[b];
    const float4 q = *reinterpret_cast<const float4*>(item_emb + (size_t)it * DD + d0);
    const int* __restrict__ hrow = hist_items + (size_t)b * LL;

    float4 acc = make_float4(0.f, 0.f, 0.f, 0.f);
    int l = sub;
    for (; l + 8 < len; l += 16) {
        const int j0 = hrow[l];
        const int j1 = hrow[l + 8];
        const float4 y0 = *reinterpret_cast<const float4*>(implicit_emb + (size_t)j0 * DD + d0);
        const float4 y1 = *reinterpret_cast<const float4*>(implicit_emb + (size_t)j1 * DD + d0);
        acc.x += y0.x; acc.y += y0.y; acc.z += y0.z; acc.w += y0.w;
        acc.x += y1.x; acc.y += y1.y; acc.z += y1.z; acc.w += y1.w;
    }
    if (l < len) {
        const int j = hrow[l];
        const float4 y = *reinterpret_cast<const float4*>(implicit_emb + (size_t)j * DD + d0);
        acc.x += y.x; acc.y += y.y; acc.z += y.z; acc.w += y.w;
    }

    acc.x += __shfl_xor(acc.x, 32, 64);
    acc.y += __shfl_xor(acc.y, 32, 64);
    acc.z += __shfl_xor(acc.z, 32, 64);
    acc.w += __shfl_xor(acc.w, 32, 64);

    float s = q.x * acc.x + q.y * acc.y + q.z * acc.z + q.w * acc.w;
    s += __shfl_down(s, 16, 64);
    s += __shfl_down(s, 8, 64);
    s += __shfl_down(s, 4, 64);
    s += __shfl_down(s, 2, 64);
    s += __shfl_down(s, 1, 64);

    __shared__ float partial[4];
    if (lane == 0) partial[w] = s;
    __syncthreads();

    if (w == 0) {
        const int u = user_ids[b];
        const float4 p = *reinterpret_cast<const float4*>(user_emb + (size_t)u * DD + d0);
        float bs = p.x * q.x + p.y * q.y + p.z * q.z + p.w * q.w;
        bs += __shfl_down(bs, 16, 64);
        bs += __shfl_down(bs, 8, 64);
        bs += __shfl_down(bs, 4, 64);
        bs += __shfl_down(bs, 2, 64);
        bs += __shfl_down(bs, 1, 64);
        if (lane == 0) {
            const float S = partial[0] + partial[1] + partial[2] + partial[3];
            const float nr = (len > 0) ? rsqrtf((float)len) : 0.f;
            out[b] = global_bias[0] + user_bias[u] + item_bias[it] + bs + nr * S;
        }
    }
}

extern "C" void kernel_launch(void* const* d_in, const int* in_sizes, int n_in,
                              void* d_out, int out_size, void* d_ws, size_t ws_size,
                              hipStream_t stream) {
    const int*   user_ids     = (const int*)d_in[0];
    const int*   item_ids     = (const int*)d_in[1];
    const int*   hist_items   = (const int*)d_in[2];
    const int*   hist_len     = (const int*)d_in[3];
    const float* user_emb     = (const float*)d_in[4];
    const float* item_emb     = (const float*)d_in[5];
    const float* implicit_emb = (const float*)d_in[6];
    const float* user_bias    = (const float*)d_in[7];
    const float* item_bias    = (const float*)d_in[8];
    const float* global_bias  = (const float*)d_in[9];
    float* out = (float*)d_out;
    char*  ws  = (char*)d_ws;

    if (ws_size >= (size_t)WS_FULL) {
        __half* imp16 = (__half*)(ws + OFF_IMP16);
        __half* Q     = (__half*)(ws + OFF_Q);
        int*    sidx  = (int*)   (ws + OFF_SIDX);
        int*    soffs = (int*)   (ws + OFF_OFFS);
        float*  part  = (float*) (ws + OFF_PART);
        float*  base  = (float*) (ws + OFF_BASE);
        float*  norm  = (float*) (ws + OFF_NORM);

        k0_prep<<<CONV_BLOCKS + QB_BLOCKS + SORT_BLOCKS, 256, 0, stream>>>(
            user_ids, item_ids, hist_items, hist_len,
            user_emb, item_emb, implicit_emb,
            user_bias, item_bias, global_bias,
            imp16, Q, sidx, soffs, base, norm);

        k2_gather<<<K2_BLOCKS, 256, 0, stream>>>(imp16, Q, sidx, soffs, part);

        k3_final<<<(BB + 255) / 256, 256, 0, stream>>>(base, norm, part, out);
    } else if (ws_size >= (size_t)IMP16_BYTES) {
        __half* imp16 = (__half*)ws;
        const int n8 = 1600000;
        convert_kernel<<<(n8 + 255) / 256, 256, 0, stream>>>(implicit_emb, imp16, n8);
        svdpp_fp16_kernel<<<BB, 256, 0, stream>>>(
            user_ids, item_ids, hist_items, hist_len,
            user_emb, item_emb, imp16,
            user_bias, item_bias, global_bias, out);
    } else {
        svdpp_fp32_kernel<<<BB, 256, 0, stream>>>(
            user_ids, item_ids, hist_items, hist_len,
            user_emb, item_emb, implicit_emb,
            user_bias, item_bias, global_bias, out);
    }
}

// Round 6
// 47.759 us; speedup vs baseline: 3.2104x; 1.4296x over previous
//
#include <hip/hip_runtime.h>
#include <hip/hip_fp16.h>

// SVD++ scoring. out[b] = mu + b_u + b_i + q.p + rsqrt(len)*sum_{l<len} q . y[hist[b][l]]
// R6: whole-table fp16 gather (R3 base), MLP-deepened:
//   - quarter-wave (16-lane) row reads: one 256B fp16 row per 16 lanes (dwordx4),
//     4 rows per wave-instruction
//   - unroll 4 -> 16 rows in flight per wave
//   - indices LDS-staged; epilogue fused (p.q + biases + norm*S) per block.
// Convert kernel (fp32->fp16 table in ws) unchanged from R3.

#define BB 8192
#define DD 128
#define LL 200
#define IMP16_BYTES 25600000u

struct __align__(16) half8 { __half2 h[4]; };
struct __align__(8)  half4 { __half2 a, b; };

__global__ __launch_bounds__(256) void convert_kernel(
    const float* __restrict__ in, __half* __restrict__ out, int n8)
{
    int i = blockIdx.x * blockDim.x + threadIdx.x;   // one 8-float chunk per thread
    if (i >= n8) return;
    const float4 v0 = reinterpret_cast<const float4*>(in)[2 * i];
    const float4 v1 = reinterpret_cast<const float4*>(in)[2 * i + 1];
    half4 h0, h1;
    h0.a = __floats2half2_rn(v0.x, v0.y); h0.b = __floats2half2_rn(v0.z, v0.w);
    h1.a = __floats2half2_rn(v1.x, v1.y); h1.b = __floats2half2_rn(v1.z, v1.w);
    reinterpret_cast<half4*>(out)[2 * i]     = h0;
    reinterpret_cast<half4*>(out)[2 * i + 1] = h1;
}

__device__ __forceinline__ float dot8(const half8 r, const float4 q0, const float4 q1) {
    const float2 a = __half22float2(r.h[0]);
    const float2 b = __half22float2(r.h[1]);
    const float2 c = __half22float2(r.h[2]);
    const float2 d = __half22float2(r.h[3]);
    return a.x * q0.x + a.y * q0.y + b.x * q0.z + b.y * q0.w
         + c.x * q1.x + c.y * q1.y + d.x * q1.z + d.y * q1.w;
}

__global__ __launch_bounds__(256, 4) void svdpp_gather16(
    const int* __restrict__ user_ids,
    const int* __restrict__ item_ids,
    const int* __restrict__ hist_items,
    const int* __restrict__ hist_len,
    const float* __restrict__ user_emb,
    const float* __restrict__ item_emb,
    const __half* __restrict__ imp16,
    const float* __restrict__ user_bias,
    const float* __restrict__ item_bias,
    const float* __restrict__ global_bias,
    float* __restrict__ out)
{
    const int b   = blockIdx.x;           // one block per batch element
    const int tid = threadIdx.x;
    const int qid = tid >> 4;             // 16 quarter-waves (16 lanes each)
    const int gl  = tid & 15;             // 8 dims per lane: [gl*8, gl*8+8)

    __shared__ int   hidx[LL];
    __shared__ float part[16];

    const int len = hist_len[b];
    const int it  = item_ids[b];
    if (tid < LL) hidx[tid] = hist_items[(size_t)b * LL + tid];
    __syncthreads();

    const float* qp = item_emb + (size_t)it * DD + gl * 8;
    const float4 q0 = *reinterpret_cast<const float4*>(qp);
    const float4 q1 = *reinterpret_cast<const float4*>(qp + 4);

    float s = 0.f;
    int l = qid;                          // quarter-wave qid owns positions qid+16k
    for (; l + 48 < len; l += 64) {       // unroll 4: 16 rows in flight per wave
        const int j0 = hidx[l];
        const int j1 = hidx[l + 16];
        const int j2 = hidx[l + 32];
        const int j3 = hidx[l + 48];
        const half8 r0 = *reinterpret_cast<const half8*>(imp16 + (size_t)j0 * DD + gl * 8);
        const half8 r1 = *reinterpret_cast<const half8*>(imp16 + (size_t)j1 * DD + gl * 8);
        const half8 r2 = *reinterpret_cast<const half8*>(imp16 + (size_t)j2 * DD + gl * 8);
        const half8 r3 = *reinterpret_cast<const half8*>(imp16 + (size_t)j3 * DD + gl * 8);
        s += dot8(r0, q0, q1);
        s += dot8(r1, q0, q1);
        s += dot8(r2, q0, q1);
        s += dot8(r3, q0, q1);
    }
    for (; l < len; l += 16) {
        const int j = hidx[l];
        const half8 r = *reinterpret_cast<const half8*>(imp16 + (size_t)j * DD + gl * 8);
        s += dot8(r, q0, q1);
    }

    // reduce within the 16-lane quarter (xor masks 1..8 stay inside the group)
    s += __shfl_xor(s, 8, 64);
    s += __shfl_xor(s, 4, 64);
    s += __shfl_xor(s, 2, 64);
    s += __shfl_xor(s, 1, 64);
    if (gl == 0) part[qid] = s;
    __syncthreads();

    if (tid < 16) {                       // quarter 0: p.q + combine (gl == tid)
        const int u = user_ids[b];
        const float* pp = user_emb + (size_t)u * DD + tid * 8;
        const float4 p0 = *reinterpret_cast<const float4*>(pp);
        const float4 p1 = *reinterpret_cast<const float4*>(pp + 4);
        float pd = p0.x * q0.x + p0.y * q0.y + p0.z * q0.z + p0.w * q0.w
                 + p1.x * q1.x + p1.y * q1.y + p1.z * q1.z + p1.w * q1.w;
        float S = part[tid];
        pd += __shfl_xor(pd, 8, 64);  S += __shfl_xor(S, 8, 64);
        pd += __shfl_xor(pd, 4, 64);  S += __shfl_xor(S, 4, 64);
        pd += __shfl_xor(pd, 2, 64);  S += __shfl_xor(S, 2, 64);
        pd += __shfl_xor(pd, 1, 64);  S += __shfl_xor(S, 1, 64);
        if (tid == 0) {
            const float nr = (len > 0) ? rsqrtf((float)len) : 0.f;
            out[b] = global_bias[0] + user_bias[u] + item_bias[it] + pd + nr * S;
        }
    }
}

// Fallback: fp32 direct gather (R2 kernel), used only if ws can't hold the table.
__global__ __launch_bounds__(256) void svdpp_fp32_kernel(
    const int* __restrict__ user_ids,
    const int* __restrict__ item_ids,
    const int* __restrict__ hist_items,
    const int* __restrict__ hist_len,
    const float* __restrict__ user_emb,
    const float* __restrict__ item_emb,
    const float* __restrict__ implicit_emb,
    const float* __restrict__ user_bias,
    const float* __restrict__ item_bias,
    const float* __restrict__ global_bias,
    float* __restrict__ out)
{
    const int b    = blockIdx.x;
    const int tid  = threadIdx.x;
    const int w    = tid >> 6;
    const int lane = tid & 63;
    const int half = lane >> 5;
    const int sub  = (w << 1) | half;
    const int d0   = (lane & 31) << 2;

    const int len = hist_len[b];
    const int it  = item_ids[b];
    const float4 q = *reinterpret_cast<const float4*>(item_emb + (size_t)it * DD + d0);
    const int* __restrict__ hrow = hist_items + (size_t)b * LL;

    float4 acc = make_float4(0.f, 0.f, 0.f, 0.f);
    int l = sub;
    for (; l + 8 < len; l += 16) {
        const int j0 = hrow[l];
        const int j1 = hrow[l + 8];
        const float4 y0 = *reinterpret_cast<const float4*>(implicit_emb + (size_t)j0 * DD + d0);
        const float4 y1 = *reinterpret_cast<const float4*>(implicit_emb + (size_t)j1 * DD + d0);
        acc.x += y0.x; acc.y += y0.y; acc.z += y0.z; acc.w += y0.w;
        acc.x += y1.x; acc.y += y1.y; acc.z += y1.z; acc.w += y1.w;
    }
    if (l < len) {
        const int j = hrow[l];
        const float4 y = *reinterpret_cast<const float4*>(implicit_emb + (size_t)j * DD + d0);
        acc.x += y.x; acc.y += y.y; acc.z += y.z; acc.w += y.w;
    }

    acc.x += __shfl_xor(acc.x, 32, 64);
    acc.y += __shfl_xor(acc.y, 32, 64);
    acc.z += __shfl_xor(acc.z, 32, 64);
    acc.w += __shfl_xor(acc.w, 32, 64);

    float s = q.x * acc.x + q.y * acc.y + q.z * acc.z + q.w * acc.w;
    s += __shfl_down(s, 16, 64);
    s += __shfl_down(s, 8, 64);
    s += __shfl_down(s, 4, 64);
    s += __shfl_down(s, 2, 64);
    s += __shfl_down(s, 1, 64);

    __shared__ float partial[4];
    if (lane == 0) partial[w] = s;
    __syncthreads();

    if (w == 0) {
        const int u = user_ids[b];
        const float4 p = *reinterpret_cast<const float4*>(user_emb + (size_t)u * DD + d0);
        float bs = p.x * q.x + p.y * q.y + p.z * q.z + p.w * q.w;
        bs += __shfl_down(bs, 16, 64);
        bs += __shfl_down(bs, 8, 64);
        bs += __shfl_down(bs, 4, 64);
        bs += __shfl_down(bs, 2, 64);
        bs += __shfl_down(bs, 1, 64);
        if (lane == 0) {
            const float S = partial[0] + partial[1] + partial[2] + partial[3];
            const float nr = (len > 0) ? rsqrtf((float)len) : 0.f;
            out[b] = global_bias[0] + user_bias[u] + item_bias[it] + bs + nr * S;
        }
    }
}

extern "C" void kernel_launch(void* const* d_in, const int* in_sizes, int n_in,
                              void* d_out, int out_size, void* d_ws, size_t ws_size,
                              hipStream_t stream) {
    const int*   user_ids     = (const int*)d_in[0];
    const int*   item_ids     = (const int*)d_in[1];
    const int*   hist_items   = (const int*)d_in[2];
    const int*   hist_len     = (const int*)d_in[3];
    const float* user_emb     = (const float*)d_in[4];
    const float* item_emb     = (const float*)d_in[5];
    const float* implicit_emb = (const float*)d_in[6];
    const float* user_bias    = (const float*)d_in[7];
    const float* item_bias    = (const float*)d_in[8];
    const float* global_bias  = (const float*)d_in[9];
    float* out = (float*)d_out;

    if (ws_size >= (size_t)IMP16_BYTES) {
        __half* imp16 = (__half*)d_ws;
        const int n8 = 1600000;                       // 12.8M floats / 8
        convert_kernel<<<(n8 + 255) / 256, 256, 0, stream>>>(implicit_emb, imp16, n8);
        svdpp_gather16<<<BB, 256, 0, stream>>>(
            user_ids, item_ids, hist_items, hist_len,
            user_emb, item_emb, imp16,
            user_bias, item_bias, global_bias, out);
    } else {
        svdpp_fp32_kernel<<<BB, 256, 0, stream>>>(
            user_ids, item_ids, hist_items, hist_len,
            user_emb, item_emb, implicit_emb,
            user_bias, item_bias, global_bias, out);
    }
}